// Round 1
// baseline (145.672 us; speedup 1.0000x reference)
//
#include <hip/hip_runtime.h>
#include <math.h>

// Deformation4D: N=1M gaussians, K_NB=10 neighbors, K_TOTAL=300 control points.
// Strategy: per-block LDS table of precomputed per-CP {R(9), b(3), q_raw(4)}
// where b = pos + trans - R*pos, so per neighbor only 16 weighted accumulates.
// deformed_mean = (sum w_k R_k) * mean + sum w_k b_k  (exact refactor of ref).
// blended_rot uses RAW ctrl quats (ref normalizes only inside R conversion).

template <int KNB>
__global__ __launch_bounds__(256) void deform_kernel(
    const float* __restrict__ means,
    const float* __restrict__ quats,
    const float* __restrict__ weights,
    const float* __restrict__ ctrl_trans,
    const float* __restrict__ ctrl_rot,
    const float* __restrict__ ctrl_pos,
    const int*   __restrict__ indices,
    float* __restrict__ out_means,
    float* __restrict__ out_quats,
    int N, int K_TOTAL)
{
    // stride 5 float4s per CP (16 floats used + 4 pad) -> bank spread
    extern __shared__ float4 s4[];

    for (int cp = threadIdx.x; cp < K_TOTAL; cp += blockDim.x) {
        float qw = ctrl_rot[cp * 4 + 0];
        float qx = ctrl_rot[cp * 4 + 1];
        float qy = ctrl_rot[cp * 4 + 2];
        float qz = ctrl_rot[cp * 4 + 3];
        float n  = sqrtf(qw * qw + qx * qx + qy * qy + qz * qz);
        float inv = 1.0f / fmaxf(n, 1e-8f);
        float w = qw * inv, x = qx * inv, y = qy * inv, z = qz * inv;
        float R00 = 1.0f - 2.0f * (y * y + z * z);
        float R01 = 2.0f * (x * y - w * z);
        float R02 = 2.0f * (x * z + w * y);
        float R10 = 2.0f * (x * y + w * z);
        float R11 = 1.0f - 2.0f * (x * x + z * z);
        float R12 = 2.0f * (y * z - w * x);
        float R20 = 2.0f * (x * z - w * y);
        float R21 = 2.0f * (y * z + w * x);
        float R22 = 1.0f - 2.0f * (x * x + y * y);
        float px = ctrl_pos[cp * 3 + 0];
        float py = ctrl_pos[cp * 3 + 1];
        float pz = ctrl_pos[cp * 3 + 2];
        float tx = ctrl_trans[cp * 3 + 0];
        float ty = ctrl_trans[cp * 3 + 1];
        float tz = ctrl_trans[cp * 3 + 2];
        float bx = px + tx - (R00 * px + R01 * py + R02 * pz);
        float by = py + ty - (R10 * px + R11 * py + R12 * pz);
        float bz = pz + tz - (R20 * px + R21 * py + R22 * pz);
        s4[cp * 5 + 0] = make_float4(R00, R01, R02, R10);
        s4[cp * 5 + 1] = make_float4(R11, R12, R20, R21);
        s4[cp * 5 + 2] = make_float4(R22, bx, by, bz);
        s4[cp * 5 + 3] = make_float4(qw, qx, qy, qz);   // raw quat for blending
    }
    __syncthreads();

    int i = blockIdx.x * blockDim.x + threadIdx.x;
    if (i >= N) return;

    const int*   idx_row = indices + (long long)i * KNB;
    const float* w_row   = weights + (long long)i * KNB;

    float acc[16];
#pragma unroll
    for (int j = 0; j < 16; j++) acc[j] = 0.0f;

#pragma unroll
    for (int k = 0; k < KNB; k++) {
        int   cp = idx_row[k];
        float w  = w_row[k];
        float4 a = s4[cp * 5 + 0];
        float4 b = s4[cp * 5 + 1];
        float4 c = s4[cp * 5 + 2];
        float4 d = s4[cp * 5 + 3];
        acc[0]  = fmaf(w, a.x, acc[0]);
        acc[1]  = fmaf(w, a.y, acc[1]);
        acc[2]  = fmaf(w, a.z, acc[2]);
        acc[3]  = fmaf(w, a.w, acc[3]);
        acc[4]  = fmaf(w, b.x, acc[4]);
        acc[5]  = fmaf(w, b.y, acc[5]);
        acc[6]  = fmaf(w, b.z, acc[6]);
        acc[7]  = fmaf(w, b.w, acc[7]);
        acc[8]  = fmaf(w, c.x, acc[8]);
        acc[9]  = fmaf(w, c.y, acc[9]);
        acc[10] = fmaf(w, c.z, acc[10]);
        acc[11] = fmaf(w, c.w, acc[11]);
        acc[12] = fmaf(w, d.x, acc[12]);
        acc[13] = fmaf(w, d.y, acc[13]);
        acc[14] = fmaf(w, d.z, acc[14]);
        acc[15] = fmaf(w, d.w, acc[15]);
    }

    float mx = means[i * 3 + 0];
    float my = means[i * 3 + 1];
    float mz = means[i * 3 + 2];

    // acc layout: [R00 R01 R02 R10][R11 R12 R20 R21][R22 bx by bz][qw qx qy qz]
    float dmx = acc[0] * mx + acc[1] * my + acc[2] * mz + acc[9];
    float dmy = acc[3] * mx + acc[4] * my + acc[5] * mz + acc[10];
    float dmz = acc[6] * mx + acc[7] * my + acc[8] * mz + acc[11];

    out_means[i * 3 + 0] = dmx;
    out_means[i * 3 + 1] = dmy;
    out_means[i * 3 + 2] = dmz;

    // normalize blended quaternion
    float bw = acc[12], bx = acc[13], by = acc[14], bz = acc[15];
    float n  = sqrtf(bw * bw + bx * bx + by * by + bz * bz);
    float inv = 1.0f / fmaxf(n, 1e-8f);
    bw *= inv; bx *= inv; by *= inv; bz *= inv;

    // gaussian quaternion (raw, as in reference)
    float4 g = ((const float4*)quats)[i];
    float gw = g.x, gx = g.y, gy = g.z, gz = g.w;

    // quaternion_multiply(blended, gaussian), (w,x,y,z)
    float ow = bw * gw - bx * gx - by * gy - bz * gz;
    float ox = bw * gx + bx * gw + by * gz - bz * gy;
    float oy = bw * gy - bx * gz + by * gw + bz * gx;
    float oz = bw * gz + bx * gy - by * gx + bz * gw;

    float4* oq = (float4*)(out_quats + (long long)i * 4);
    *oq = make_float4(ow, ox, oy, oz);
}

// generic fallback (runtime K_NB)
__global__ __launch_bounds__(256) void deform_kernel_generic(
    const float* __restrict__ means,
    const float* __restrict__ quats,
    const float* __restrict__ weights,
    const float* __restrict__ ctrl_trans,
    const float* __restrict__ ctrl_rot,
    const float* __restrict__ ctrl_pos,
    const int*   __restrict__ indices,
    float* __restrict__ out_means,
    float* __restrict__ out_quats,
    int N, int K_NB, int K_TOTAL)
{
    extern __shared__ float4 s4[];
    for (int cp = threadIdx.x; cp < K_TOTAL; cp += blockDim.x) {
        float qw = ctrl_rot[cp * 4 + 0];
        float qx = ctrl_rot[cp * 4 + 1];
        float qy = ctrl_rot[cp * 4 + 2];
        float qz = ctrl_rot[cp * 4 + 3];
        float n  = sqrtf(qw * qw + qx * qx + qy * qy + qz * qz);
        float inv = 1.0f / fmaxf(n, 1e-8f);
        float w = qw * inv, x = qx * inv, y = qy * inv, z = qz * inv;
        float R00 = 1.0f - 2.0f * (y * y + z * z);
        float R01 = 2.0f * (x * y - w * z);
        float R02 = 2.0f * (x * z + w * y);
        float R10 = 2.0f * (x * y + w * z);
        float R11 = 1.0f - 2.0f * (x * x + z * z);
        float R12 = 2.0f * (y * z - w * x);
        float R20 = 2.0f * (x * z - w * y);
        float R21 = 2.0f * (y * z + w * x);
        float R22 = 1.0f - 2.0f * (x * x + y * y);
        float px = ctrl_pos[cp * 3 + 0];
        float py = ctrl_pos[cp * 3 + 1];
        float pz = ctrl_pos[cp * 3 + 2];
        float tx = ctrl_trans[cp * 3 + 0];
        float ty = ctrl_trans[cp * 3 + 1];
        float tz = ctrl_trans[cp * 3 + 2];
        float bx = px + tx - (R00 * px + R01 * py + R02 * pz);
        float by = py + ty - (R10 * px + R11 * py + R12 * pz);
        float bz = pz + tz - (R20 * px + R21 * py + R22 * pz);
        s4[cp * 5 + 0] = make_float4(R00, R01, R02, R10);
        s4[cp * 5 + 1] = make_float4(R11, R12, R20, R21);
        s4[cp * 5 + 2] = make_float4(R22, bx, by, bz);
        s4[cp * 5 + 3] = make_float4(qw, qx, qy, qz);
    }
    __syncthreads();

    int i = blockIdx.x * blockDim.x + threadIdx.x;
    if (i >= N) return;

    const int*   idx_row = indices + (long long)i * K_NB;
    const float* w_row   = weights + (long long)i * K_NB;

    float acc[16];
#pragma unroll
    for (int j = 0; j < 16; j++) acc[j] = 0.0f;

    for (int k = 0; k < K_NB; k++) {
        int   cp = idx_row[k];
        float w  = w_row[k];
        float4 a = s4[cp * 5 + 0];
        float4 b = s4[cp * 5 + 1];
        float4 c = s4[cp * 5 + 2];
        float4 d = s4[cp * 5 + 3];
        acc[0]  = fmaf(w, a.x, acc[0]);
        acc[1]  = fmaf(w, a.y, acc[1]);
        acc[2]  = fmaf(w, a.z, acc[2]);
        acc[3]  = fmaf(w, a.w, acc[3]);
        acc[4]  = fmaf(w, b.x, acc[4]);
        acc[5]  = fmaf(w, b.y, acc[5]);
        acc[6]  = fmaf(w, b.z, acc[6]);
        acc[7]  = fmaf(w, b.w, acc[7]);
        acc[8]  = fmaf(w, c.x, acc[8]);
        acc[9]  = fmaf(w, c.y, acc[9]);
        acc[10] = fmaf(w, c.z, acc[10]);
        acc[11] = fmaf(w, c.w, acc[11]);
        acc[12] = fmaf(w, d.x, acc[12]);
        acc[13] = fmaf(w, d.y, acc[13]);
        acc[14] = fmaf(w, d.z, acc[14]);
        acc[15] = fmaf(w, d.w, acc[15]);
    }

    float mx = means[i * 3 + 0];
    float my = means[i * 3 + 1];
    float mz = means[i * 3 + 2];

    float dmx = acc[0] * mx + acc[1] * my + acc[2] * mz + acc[9];
    float dmy = acc[3] * mx + acc[4] * my + acc[5] * mz + acc[10];
    float dmz = acc[6] * mx + acc[7] * my + acc[8] * mz + acc[11];

    out_means[i * 3 + 0] = dmx;
    out_means[i * 3 + 1] = dmy;
    out_means[i * 3 + 2] = dmz;

    float bw = acc[12], bx = acc[13], by = acc[14], bz = acc[15];
    float n  = sqrtf(bw * bw + bx * bx + by * by + bz * bz);
    float inv = 1.0f / fmaxf(n, 1e-8f);
    bw *= inv; bx *= inv; by *= inv; bz *= inv;

    float4 g = ((const float4*)quats)[i];
    float gw = g.x, gx = g.y, gy = g.z, gz = g.w;

    float ow = bw * gw - bx * gx - by * gy - bz * gz;
    float ox = bw * gx + bx * gw + by * gz - bz * gy;
    float oy = bw * gy - bx * gz + by * gw + bz * gx;
    float oz = bw * gz + bx * gy - by * gx + bz * gw;

    float4* oq = (float4*)(out_quats + (long long)i * 4);
    *oq = make_float4(ow, ox, oy, oz);
}

extern "C" void kernel_launch(void* const* d_in, const int* in_sizes, int n_in,
                              void* d_out, int out_size, void* d_ws, size_t ws_size,
                              hipStream_t stream) {
    const float* means      = (const float*)d_in[0];
    const float* quats      = (const float*)d_in[1];
    const float* weights    = (const float*)d_in[2];
    const float* ctrl_trans = (const float*)d_in[3];
    const float* ctrl_rot   = (const float*)d_in[4];
    const float* ctrl_pos   = (const float*)d_in[5];
    const int*   indices    = (const int*)d_in[6];

    int N       = in_sizes[0] / 3;
    int K_NB    = in_sizes[2] / N;       // weights is N*K_NB
    int K_TOTAL = in_sizes[3] / 3;       // ctrl_translations is K_TOTAL*3

    float* out_means = (float*)d_out;
    float* out_quats = (float*)d_out + (long long)N * 3;

    int block = 256;
    int grid  = (N + block - 1) / block;
    size_t smem = (size_t)K_TOTAL * 5 * sizeof(float4);

    if (K_NB == 10) {
        deform_kernel<10><<<grid, block, smem, stream>>>(
            means, quats, weights, ctrl_trans, ctrl_rot, ctrl_pos, indices,
            out_means, out_quats, N, K_TOTAL);
    } else {
        deform_kernel_generic<<<grid, block, smem, stream>>>(
            means, quats, weights, ctrl_trans, ctrl_rot, ctrl_pos, indices,
            out_means, out_quats, N, K_NB, K_TOTAL);
    }
}